// Round 10
// baseline (202.326 us; speedup 1.0000x reference)
//
#include <hip/hip_runtime.h>
#include <math.h>

// B=32 graphs, N=1024 nodes, D=128 in-dim, C=64 out-dim, K=16.
#define OUT_ELEMS 2097152   // 32768*64
#define EDGE_ELEMS 524288   // 32*1024*16

__device__ __forceinline__ unsigned int rotl32(unsigned int x, int r){
  return (x << r) | (x >> (32 - r));
}

// JAX partitionable threefry, key (0,1): counter = (0, e); out = o0 ^ o1.
__device__ __forceinline__ unsigned int tf_bits_part(unsigned int e){
  unsigned int x0 = 0u, x1 = e;
  const unsigned int ks1 = 1u;
  const unsigned int ks2 = 0x1BD11BDBu;
  x1 += ks1;
#define TFR(r) { x0 += x1; x1 = rotl32(x1, r); x1 ^= x0; }
  TFR(13) TFR(15) TFR(26) TFR(6)
  x0 += ks1; x1 += ks2 + 1u;
  TFR(17) TFR(29) TFR(16) TFR(24)
  x0 += ks2; x1 += 0u + 2u;
  TFR(13) TFR(15) TFR(26) TFR(6)
  x0 += 0u;  x1 += ks1 + 3u;
  TFR(17) TFR(29) TFR(16) TFR(24)
  x0 += ks1; x1 += ks2 + 4u;
  TFR(13) TFR(15) TFR(26) TFR(6)
  x0 += ks2; x1 += 0u + 5u;
#undef TFR
  return x0 ^ x1;
}

// hardware f64 reciprocal + 2 Newton steps: rel err ~1e-16.
__device__ __forceinline__ double rcp64(double x){
  double r;
  asm("v_rcp_f64 %0, %1" : "=v"(r) : "v"(x));
  double e = fma(-x, r, 1.0); r = fma(r, e, r);
  e = fma(-x, r, 1.0); r = fma(r, e, r);
  return r;
}

// fast e^x for x in [-740, ~1]; rel err ~2e-11 (deg-9).
__device__ __forceinline__ double fast_exp(double x){
  double fn = __builtin_rint(x * 1.4426950408889634);
  int n = (int)fn;
  double r = fma(fn, -0.6931471803691238, x);
  r = fma(fn, -1.9082149292705877e-10, r);
  double p = 2.7557319223985893e-06;
  p = fma(r, p, 2.4801587301587302e-05);
  p = fma(r, p, 1.9841269841269841e-04);
  p = fma(r, p, 1.3888888888888889e-03);
  p = fma(r, p, 8.3333333333333333e-03);
  p = fma(r, p, 4.1666666666666664e-02);
  p = fma(r, p, 1.6666666666666666e-01);
  p = fma(r, p, 0.5);
  p = fma(r, p, 1.0);
  p = fma(r, p, 1.0);
  double scale = __longlong_as_double(((long long)(n + 1023)) << 52);
  return p * scale;
}

// fast ln(x), normal positive x; atanh form; abs err ~2e-11.
__device__ __forceinline__ double fast_log(double x){
  long long bx = __double_as_longlong(x);
  long long e = (bx >> 52) - 1023;
  double m = __longlong_as_double((bx & 0xFFFFFFFFFFFFFll) |
                                  0x3FF0000000000000ll);
  int big = m > 1.4142135623730951;
  m = big ? 0.5 * m : m;
  e += big;
  double s = (m - 1.0) * rcp64(m + 1.0);
  double s2 = s * s;
  double p = fma(s2, 2.0/11.0, 2.0/9.0);
  p = fma(s2, p, 2.0/7.0);
  p = fma(s2, p, 2.0/5.0);
  p = fma(s2, p, 2.0/3.0);
  double lm = fma(s * s2, p, 2.0 * s);
  return fma((double)e, 0.6931471805599453, lm);
}

// f32 squared distance; arithmetic identical to v16's score head.
__device__ __forceinline__ float dist2_f32(
    const float* __restrict__ og, const float* __restrict__ hrowf,
    unsigned int jc){
  const float4* cp4 = (const float4*)(og + ((size_t)jc << 6));
  const float4* hp4 = (const float4*)hrowf;
  float a0 = 0.0f, a1 = 0.0f, a2 = 0.0f, a3 = 0.0f;
  #pragma unroll 4
  for (int ch = 0; ch < 16; ++ch){
    float4 cf = cp4[ch];
    float4 hf = hp4[ch];
    float d0 = hf.x - cf.x;
    float d1 = hf.y - cf.y;
    float d2 = hf.z - cf.z;
    float d3 = hf.w - cf.w;
    a0 = fmaf(d0, d0, a0);
    a1 = fmaf(d1, d1, a1);
    a2 = fmaf(d2, d2, a2);
    a3 = fmaf(d3, d3, a3);
  }
  return (a0 + a1) + (a2 + a3);
}

// order-preserving u64 pack, low 10 bits = inverted index (v16 identical).
__device__ __forceinline__ unsigned long long pack_key(double sc,
                                                       unsigned int jc){
  unsigned long long kb = (unsigned long long)__double_as_longlong(sc);
  kb ^= (unsigned long long)(((long long)kb) >> 63) | 0x8000000000000000ull;
  return (kb & ~1023ull) | (unsigned long long)(1023u - jc);
}

// exact f64 tail — keys bit-identical to v16's score_cand32.
__device__ __forceinline__ unsigned long long tail64(
    float accf, unsigned int bits, unsigned int jc, double Td, bool act){
  if (!act) return 0ull;
  double sgm = fast_exp(-Td * (double)accf);
  float f = __uint_as_float(0x3f800000u | (bits >> 9)) - 1.0f;
  double u = (f > 0.0f) ? (double)f : 1.1754943508222875e-38;
  double w = -fast_log(u);
  double z = -fast_log(w);
  double sc = sgm + z;
  return pack_key(sc, jc);
}

// fast f32 tail; |score - tail64 score| <= ~5e-7 (HW exp/log 1-2 ulp).
__device__ __forceinline__ unsigned long long tail32(
    float accf, unsigned int bits, unsigned int jc, float Tf, bool act){
  if (!act) return 0ull;
  float sg = __expf(-Tf * accf);
  float f = __uint_as_float(0x3f800000u | (bits >> 9)) - 1.0f;
  float uf = (f > 0.0f) ? f : 1.17549435e-38f;   // FLT_MIN (normal)
  float wv = -__logf(uf);
  float zf = -__logf(wv);
  double sc = (double)sg + (double)zf;
  return pack_key(sc, jc);
}

// inverse of pack_key's order map (low 10 index bits zeroed: ~2e-13 rel).
__device__ __forceinline__ double key_score(unsigned long long k){
  unsigned long long orig = (k >> 63) ? (k ^ 0x8000000000000000ull) : ~k;
  return __longlong_as_double((long long)(orig & ~1023ull));
}

// Full descending bitonic sort of u64 keys across 64 lanes.
__device__ __forceinline__ unsigned long long bitonic64_desc(
    unsigned long long key, int lane){
  #pragma unroll
  for (int k = 2; k <= 64; k <<= 1){
    #pragma unroll
    for (int j = k >> 1; j; j >>= 1){
      unsigned long long o = __shfl_xor(key, j, 64);
      bool keep_hi = ((lane & k) == 0) == ((lane & j) == 0);
      key = (keep_hi == (o > key)) ? o : key;
    }
  }
  return key;
}

// Full descending bitonic sort of u32 keys across 64 lanes.
__device__ __forceinline__ unsigned int bitonic32_desc(
    unsigned int key, int lane){
  #pragma unroll
  for (int k = 2; k <= 64; k <<= 1){
    #pragma unroll
    for (int j = k >> 1; j; j >>= 1){
      unsigned int o = __shfl_xor(key, j, 64);
      bool keep_hi = ((lane & k) == 0) == ((lane & j) == 0);
      key = (keep_hi == (o > key)) ? o : key;
    }
  }
  return key;
}

// ---------------- encoder ----------------
// v20: feed the f64 pipe without SMEM in the loop. v15/v19 kept s_load(W) in
// the k-loop; s_load and ds_read share lgkmcnt and w64 (64KB) thrashes the
// 16KB scalar cache -> mixed-counter waits starve the f64 pipe (~60us vs the
// ~32us saturated floor at the measured ~15cyc/wave f64 rate). v20:
//  - W: block's 16-col slice cvt'd once to f64 in LDS (16KB); inner-loop W
//    reads are broadcast ds_read_b128 (uniform addr, conflict-free).
//  - x: lane=row, row data loaded into REGISTERS in 8 chunks of 16 floats
//    (global_load_dwordx4); no x LDS, cvt from reg.
//  - cvt prekernel dropped (W/b converted in-block; identical values).
// Numerics: per (r,c) chain is k=0..127 ascending, acc=fma((double)x,
// (double)W, acc), init (double)b[c] — operand-identical to v15..v19 ->
// out BIT-IDENTICAL (absmax must read exactly 480.0).
__global__ __launch_bounds__(256, 6) void encoder_v20(
    const float* __restrict__ x, const float* __restrict__ W,
    const float* __restrict__ b, float* __restrict__ out){
  __shared__ double Wl[128 * 16];        // 16 KB f64 col-slice
  const int tid = threadIdx.x;
  const int rt = blockIdx.x >> 2;        // row tile 0..511
  const int cb = (blockIdx.x & 3) << 4;  // col base 0/16/32/48

  { // stage W slice f32 -> f64 (exact, once per block), coalesced reads
    #pragma unroll
    for (int s = 0; s < 8; ++s){
      const int idx = tid + (s << 8);    // 0..2047
      const int k = idx >> 4, c = idx & 15;
      Wl[idx] = (double)W[(k << 6) + cb + c];
    }
  }
  __syncthreads();

  const int lane = tid & 63;             // row within tile
  const int wv = tid >> 6;               // wave 0..3
  const int wc = wv << 2;                // wave's col offset in slice
  const size_t row = ((size_t)rt << 6) + (size_t)lane;
  const float4* __restrict__ xg = (const float4*)(x + (row << 7));

  double acc[4];
  #pragma unroll
  for (int j = 0; j < 4; ++j) acc[j] = (double)b[cb + wc + j];

#define ENC_STEP(xf, krow) {                                   \
    const double xk = (double)(xf);                            \
    const double* __restrict__ wp = &Wl[((krow) << 4) + wc];   \
    acc[0] = fma(xk, wp[0], acc[0]);                           \
    acc[1] = fma(xk, wp[1], acc[1]);                           \
    acc[2] = fma(xk, wp[2], acc[2]);                           \
    acc[3] = fma(xk, wp[3], acc[3]); }

  #pragma unroll 2
  for (int ch = 0; ch < 8; ++ch){        // 8 chunks of 16 k
    float4 xq[4];
    #pragma unroll
    for (int q = 0; q < 4; ++q) xq[q] = xg[(ch << 2) + q];
    #pragma unroll
    for (int q = 0; q < 4; ++q){
      const int k0 = (ch << 4) + (q << 2);
      ENC_STEP(xq[q].x, k0 + 0)
      ENC_STEP(xq[q].y, k0 + 1)
      ENC_STEP(xq[q].z, k0 + 2)
      ENC_STEP(xq[q].w, k0 + 3)
    }
  }
#undef ENC_STEP

  float* __restrict__ orow = out + (row << 6) + cb + wc;
  float4 st;
  st.x = (float)acc[0]; st.y = (float)acc[1];
  st.z = (float)acc[2]; st.w = (float)acc[3];
  *(float4*)orow = st;
}

// ---------------- edges ----------------
// FROZEN v18 (proven: 105.5 us, VGPR 32, no spill, absmax 480.0).
__global__ __launch_bounds__(256, 8) void edges_v20(
    const float* __restrict__ out32, const float* __restrict__ temp,
    float* __restrict__ rows_out, float* __restrict__ cols_out){
  __shared__ float hidf[4][64];         // 1 KB
  __shared__ unsigned int cl[4][128];   // 2 KB
  const int tid = threadIdx.x, wave = tid >> 6, lane = tid & 63;
  const int gb = blockIdx.x >> 8;
  const int i0 = (blockIdx.x & 255) << 2;
  const int r  = i0 + wave;
  const float* __restrict__ og = out32 + ((size_t)gb << 16);

  hidf[wave][lane] = og[((size_t)r << 6) + lane];

  const unsigned int base = ((unsigned int)gb << 20) | ((unsigned int)r << 10);

  // Phase 1: bits for j = m*64 + lane, with running per-lane max
  unsigned int v[16];
  unsigned int pmax = 0u;
  #pragma unroll
  for (int m = 0; m < 16; ++m){
    const unsigned int j = (unsigned int)(m << 6) + (unsigned int)lane;
    unsigned int bits = tf_bits_part(base | j);
    v[m] = (bits & ~1023u) | (1023u - j);   // low 10 bits don't feed u
    pmax = (v[m] > pmax) ? v[m] : pmax;
  }

  // Phase 2: 16th-largest lane-max (conservative surrogate for b16)
  unsigned int sorted = bitonic32_desc(pmax, lane);
  unsigned int b16p = __shfl(sorted, 15, 64);

  // conservative cut: keep j iff z_j >= z(b16') - 1.001  (score <= z + 1)
  float u16 = __uint_as_float(0x3f800000u | (b16p >> 9)) - 1.0f;
  float z16 = -__logf(-__logf(u16));
  float uc  = __expf(-__expf(-(z16 - 1.001f)));
  unsigned int cp = ((__float_as_uint(1.0f + uc) & 0x7FFFFFu) << 9) & ~1023u;

  // Phase 3: compaction of all survivors (>=16 guaranteed since cut < b16')
  int cnt = 0;
  #pragma unroll
  for (int m = 0; m < 16; ++m) cnt += (v[m] >= cp) ? 1 : 0;
  int s = cnt;
  #pragma unroll
  for (int off = 1; off < 64; off <<= 1){
    int o = __shfl_up(s, off, 64);
    s += (lane >= off) ? o : 0;
  }
  int nc = __shfl(s, 63, 64);
  nc = (nc > 128) ? 128 : nc;
  int slot = s - cnt;
  #pragma unroll
  for (int m = 0; m < 16; ++m){
    if (v[m] >= cp && slot < 128){
      cl[wave][slot] = 1023u - (v[m] & 1023u);
      ++slot;
    }
  }

  // Phase 4: scoring (f32 dist + f32 tail, guarded) + top-16
  const double Td = (double)temp[0];
  const float  Tf = temp[0];
  unsigned long long key;

  if (nc <= 64){
    const bool act1 = (lane < nc);
    const unsigned int jc1 = act1 ? cl[wave][lane] : 0u;
    const float ac1 = dist2_f32(og, &hidf[wave][0], jc1);
    const unsigned int bt1 = tf_bits_part(base | jc1);
    key = tail32(ac1, bt1, jc1, Tf, act1);
    key = bitonic64_desc(key, lane);
    // guard: adjacent top-16 gap below threshold -> exact f64 redo
    double s0 = key_score(key);
    unsigned long long kn = __shfl_down(key, 1, 64);
    double s1 = key_score(kn);
    bool tight = (lane < 16) && (key != 0ull) && ((s0 - s1) < 4e-5);
    if (__any(tight)){
      key = tail64(ac1, bt1, jc1, Td, act1);
      key = bitonic64_desc(key, lane);
    }
  } else {
    // rare two-chunk exact path (v16 verbatim semantics)
    const bool act1 = (lane < nc);
    const unsigned int jc1 = act1 ? cl[wave][lane] : 0u;
    const float ac1 = dist2_f32(og, &hidf[wave][0], jc1);
    const unsigned int bt1 = tf_bits_part(base | jc1);
    key = tail64(ac1, bt1, jc1, Td, act1);
    key = bitonic64_desc(key, lane);

    const int idx2 = 64 + lane;
    const bool act2 = (idx2 < nc);
    const unsigned int jc2 = act2 ? cl[wave][idx2] : 0u;
    const float ac2 = dist2_f32(og, &hidf[wave][0], jc2);
    const unsigned int bt2 = tf_bits_part(base | jc2);
    unsigned long long k2 = tail64(ac2, bt2, jc2, Td, act2);
    k2 = bitonic64_desc(k2, lane);
    unsigned long long kr = __shfl(k2, 63 - lane, 64);
    key = (kr > key) ? kr : key;          // elementwise top-64 (bitonic)
    #pragma unroll
    for (int j2 = 32; j2; j2 >>= 1){      // descending clean
      unsigned long long o = __shfl_xor(key, j2, 64);
      bool left = (lane & j2) == 0;
      bool take = left ? (o > key) : (o < key);
      key = take ? o : key;
    }
  }

  const int grow = (gb << 10) + r;
  if (lane < 16){
    rows_out[((size_t)grow << 4) + lane] = (float)grow;
    cols_out[((size_t)grow << 4) + lane] =
        (float)((gb << 10) + (1023 - (int)(key & 1023ull)));
  }
}

extern "C" void kernel_launch(void* const* d_in, const int* in_sizes, int n_in,
                              void* d_out, int out_size, void* d_ws, size_t ws_size,
                              hipStream_t stream){
  const float* x = (const float*)d_in[0];
  const float* W = (const float*)d_in[1];
  const float* b = (const float*)d_in[2];
  const float* T = (const float*)d_in[3];
  float* out      = (float*)d_out;
  float* rows_out = out + OUT_ELEMS;
  float* cols_out = rows_out + EDGE_ELEMS;

  encoder_v20<<<2048, 256, 0, stream>>>(x, W, b, out);
  edges_v20<<<8192, 256, 0, stream>>>(out, T, rows_out, cols_out);
}

// Round 11
// 180.017 us; speedup vs baseline: 1.1239x; 1.1239x over previous
//
#include <hip/hip_runtime.h>
#include <math.h>

// B=32 graphs, N=1024 nodes, D=128 in-dim, C=64 out-dim, K=16.
#define OUT_ELEMS 2097152   // 32768*64
#define EDGE_ELEMS 524288   // 32*1024*16

__device__ __forceinline__ unsigned int rotl32(unsigned int x, int r){
  return (x << r) | (x >> (32 - r));
}

// JAX partitionable threefry, key (0,1): counter = (0, e); out = o0 ^ o1.
__device__ __forceinline__ unsigned int tf_bits_part(unsigned int e){
  unsigned int x0 = 0u, x1 = e;
  const unsigned int ks1 = 1u;
  const unsigned int ks2 = 0x1BD11BDBu;
  x1 += ks1;
#define TFR(r) { x0 += x1; x1 = rotl32(x1, r); x1 ^= x0; }
  TFR(13) TFR(15) TFR(26) TFR(6)
  x0 += ks1; x1 += ks2 + 1u;
  TFR(17) TFR(29) TFR(16) TFR(24)
  x0 += ks2; x1 += 0u + 2u;
  TFR(13) TFR(15) TFR(26) TFR(6)
  x0 += 0u;  x1 += ks1 + 3u;
  TFR(17) TFR(29) TFR(16) TFR(24)
  x0 += ks1; x1 += ks2 + 4u;
  TFR(13) TFR(15) TFR(26) TFR(6)
  x0 += ks2; x1 += 0u + 5u;
#undef TFR
  return x0 ^ x1;
}

// hardware f64 reciprocal + 2 Newton steps: rel err ~1e-16.
__device__ __forceinline__ double rcp64(double x){
  double r;
  asm("v_rcp_f64 %0, %1" : "=v"(r) : "v"(x));
  double e = fma(-x, r, 1.0); r = fma(r, e, r);
  e = fma(-x, r, 1.0); r = fma(r, e, r);
  return r;
}

// fast e^x for x in [-740, ~1]; rel err ~2e-11 (deg-9).
__device__ __forceinline__ double fast_exp(double x){
  double fn = __builtin_rint(x * 1.4426950408889634);
  int n = (int)fn;
  double r = fma(fn, -0.6931471803691238, x);
  r = fma(fn, -1.9082149292705877e-10, r);
  double p = 2.7557319223985893e-06;
  p = fma(r, p, 2.4801587301587302e-05);
  p = fma(r, p, 1.9841269841269841e-04);
  p = fma(r, p, 1.3888888888888889e-03);
  p = fma(r, p, 8.3333333333333333e-03);
  p = fma(r, p, 4.1666666666666664e-02);
  p = fma(r, p, 1.6666666666666666e-01);
  p = fma(r, p, 0.5);
  p = fma(r, p, 1.0);
  p = fma(r, p, 1.0);
  double scale = __longlong_as_double(((long long)(n + 1023)) << 52);
  return p * scale;
}

// fast ln(x), normal positive x; atanh form; abs err ~2e-11.
__device__ __forceinline__ double fast_log(double x){
  long long bx = __double_as_longlong(x);
  long long e = (bx >> 52) - 1023;
  double m = __longlong_as_double((bx & 0xFFFFFFFFFFFFFll) |
                                  0x3FF0000000000000ll);
  int big = m > 1.4142135623730951;
  m = big ? 0.5 * m : m;
  e += big;
  double s = (m - 1.0) * rcp64(m + 1.0);
  double s2 = s * s;
  double p = fma(s2, 2.0/11.0, 2.0/9.0);
  p = fma(s2, p, 2.0/7.0);
  p = fma(s2, p, 2.0/5.0);
  p = fma(s2, p, 2.0/3.0);
  double lm = fma(s * s2, p, 2.0 * s);
  return fma((double)e, 0.6931471805599453, lm);
}

// f32 squared distance; arithmetic identical to v16's score head.
__device__ __forceinline__ float dist2_f32(
    const float* __restrict__ og, const float* __restrict__ hrowf,
    unsigned int jc){
  const float4* cp4 = (const float4*)(og + ((size_t)jc << 6));
  const float4* hp4 = (const float4*)hrowf;
  float a0 = 0.0f, a1 = 0.0f, a2 = 0.0f, a3 = 0.0f;
  #pragma unroll 4
  for (int ch = 0; ch < 16; ++ch){
    float4 cf = cp4[ch];
    float4 hf = hp4[ch];
    float d0 = hf.x - cf.x;
    float d1 = hf.y - cf.y;
    float d2 = hf.z - cf.z;
    float d3 = hf.w - cf.w;
    a0 = fmaf(d0, d0, a0);
    a1 = fmaf(d1, d1, a1);
    a2 = fmaf(d2, d2, a2);
    a3 = fmaf(d3, d3, a3);
  }
  return (a0 + a1) + (a2 + a3);
}

// order-preserving u64 pack, low 10 bits = inverted index (v16 identical).
__device__ __forceinline__ unsigned long long pack_key(double sc,
                                                       unsigned int jc){
  unsigned long long kb = (unsigned long long)__double_as_longlong(sc);
  kb ^= (unsigned long long)(((long long)kb) >> 63) | 0x8000000000000000ull;
  return (kb & ~1023ull) | (unsigned long long)(1023u - jc);
}

// exact f64 tail — keys bit-identical to v16's score_cand32.
__device__ __forceinline__ unsigned long long tail64(
    float accf, unsigned int bits, unsigned int jc, double Td, bool act){
  if (!act) return 0ull;
  double sgm = fast_exp(-Td * (double)accf);
  float f = __uint_as_float(0x3f800000u | (bits >> 9)) - 1.0f;
  double u = (f > 0.0f) ? (double)f : 1.1754943508222875e-38;
  double w = -fast_log(u);
  double z = -fast_log(w);
  double sc = sgm + z;
  return pack_key(sc, jc);
}

// fast f32 tail; |score - tail64 score| <= ~5e-7 (HW exp/log 1-2 ulp).
__device__ __forceinline__ unsigned long long tail32(
    float accf, unsigned int bits, unsigned int jc, float Tf, bool act){
  if (!act) return 0ull;
  float sg = __expf(-Tf * accf);
  float f = __uint_as_float(0x3f800000u | (bits >> 9)) - 1.0f;
  float uf = (f > 0.0f) ? f : 1.17549435e-38f;   // FLT_MIN (normal)
  float wv = -__logf(uf);
  float zf = -__logf(wv);
  double sc = (double)sg + (double)zf;
  return pack_key(sc, jc);
}

// inverse of pack_key's order map (low 10 index bits zeroed: ~2e-13 rel).
__device__ __forceinline__ double key_score(unsigned long long k){
  unsigned long long orig = (k >> 63) ? (k ^ 0x8000000000000000ull) : ~k;
  return __longlong_as_double((long long)(orig & ~1023ull));
}

// Full descending bitonic sort of u64 keys across 64 lanes.
__device__ __forceinline__ unsigned long long bitonic64_desc(
    unsigned long long key, int lane){
  #pragma unroll
  for (int k = 2; k <= 64; k <<= 1){
    #pragma unroll
    for (int j = k >> 1; j; j >>= 1){
      unsigned long long o = __shfl_xor(key, j, 64);
      bool keep_hi = ((lane & k) == 0) == ((lane & j) == 0);
      key = (keep_hi == (o > key)) ? o : key;
    }
  }
  return key;
}

// Full descending bitonic sort of u32 keys across 64 lanes.
__device__ __forceinline__ unsigned int bitonic32_desc(
    unsigned int key, int lane){
  #pragma unroll
  for (int k = 2; k <= 64; k <<= 1){
    #pragma unroll
    for (int j = k >> 1; j; j >>= 1){
      unsigned int o = __shfl_xor(key, j, 64);
      bool keep_hi = ((lane & k) == 0) == ((lane & j) == 0);
      key = (keep_hi == (o > key)) ? o : key;
    }
  }
  return key;
}

// ---------------- encoder ----------------
// v21: no SMEM in the loop (s_load is unordered on lgkmcnt -> every consume
// forced a full drain, stalling v15/v18 at ~2x the issue floor), and no
// broadcast-b128 W storm (v20's regression: ~41us of LDS port).
//  - x tile pre-cvt'd ONCE to f64 in LDS (64 KB; one cvt per element at
//    staging). Inner loop x reads = broadcast ds_read_b64 (uniform addr,
//    single-bank broadcast, cheap).
//  - W per-lane from GLOBAL f32 (lane=col, coalesced 256B/wave; 32KB W is
//    exactly L1-resident) -> vmcnt path, independent of lgkmcnt, deep
//    pipelining; 1 cvt per k per wave.
//  - lane=col, wave owns 8 rows; acc[8] f64.
// Numerics: per (r,c) chain is k=0..127 ascending, acc=fma((double)x[r][k],
// (double)W[k][c], acc), init (double)b[c] — operand-identical to v15..v20
// -> out BIT-IDENTICAL (absmax must read exactly 480.0).
__global__ __launch_bounds__(512) void encoder_v21(
    const float* __restrict__ x, const float* __restrict__ W,
    const float* __restrict__ b, float* __restrict__ out){
  __shared__ double x64[8192];          // 64 rows x 128 k, f64 = 64 KB
  const int tid = threadIdx.x;
  const size_t r0 = (size_t)blockIdx.x << 6;

  { // stage x tile f32 -> f64 (exact cvt once per element)
    const float4* xg4 = (const float4*)(x + (r0 << 7));
    #pragma unroll
    for (int s = 0; s < 4; ++s){
      const int idx = tid + (s << 9);   // 0..2047 float4s
      float4 v = xg4[idx];
      const int e0 = idx << 2;
      x64[e0 + 0] = (double)v.x;
      x64[e0 + 1] = (double)v.y;
      x64[e0 + 2] = (double)v.z;
      x64[e0 + 3] = (double)v.w;
    }
  }
  __syncthreads();

  const int lane = tid & 63;            // col
  const int wv = tid >> 6;              // wave 0..7
  const int rw = wv << 3;               // 8 rows per wave

  const double bc = (double)b[lane];
  double acc[8];
  #pragma unroll
  for (int i = 0; i < 8; ++i) acc[i] = bc;

  const double* __restrict__ xp0 = &x64[rw << 7];
  #pragma unroll 4
  for (int k = 0; k < 128; ++k){
    const double wkc = (double)W[(k << 6) + lane];   // global, L1-hot, vmcnt
    #pragma unroll
    for (int i = 0; i < 8; ++i)
      acc[i] = fma(xp0[(i << 7) + k], wkc, acc[i]);  // broadcast ds_read_b64
  }

  #pragma unroll
  for (int i = 0; i < 8; ++i)
    out[((r0 + (size_t)(rw + i)) << 6) + lane] = (float)acc[i];
}

// ---------------- edges ----------------
// FROZEN v18 (proven: 105.5 us, VGPR 32, no spill, absmax 480.0).
__global__ __launch_bounds__(256, 8) void edges_v21(
    const float* __restrict__ out32, const float* __restrict__ temp,
    float* __restrict__ rows_out, float* __restrict__ cols_out){
  __shared__ float hidf[4][64];         // 1 KB
  __shared__ unsigned int cl[4][128];   // 2 KB
  const int tid = threadIdx.x, wave = tid >> 6, lane = tid & 63;
  const int gb = blockIdx.x >> 8;
  const int i0 = (blockIdx.x & 255) << 2;
  const int r  = i0 + wave;
  const float* __restrict__ og = out32 + ((size_t)gb << 16);

  hidf[wave][lane] = og[((size_t)r << 6) + lane];

  const unsigned int base = ((unsigned int)gb << 20) | ((unsigned int)r << 10);

  // Phase 1: bits for j = m*64 + lane, with running per-lane max
  unsigned int v[16];
  unsigned int pmax = 0u;
  #pragma unroll
  for (int m = 0; m < 16; ++m){
    const unsigned int j = (unsigned int)(m << 6) + (unsigned int)lane;
    unsigned int bits = tf_bits_part(base | j);
    v[m] = (bits & ~1023u) | (1023u - j);   // low 10 bits don't feed u
    pmax = (v[m] > pmax) ? v[m] : pmax;
  }

  // Phase 2: 16th-largest lane-max (conservative surrogate for b16)
  unsigned int sorted = bitonic32_desc(pmax, lane);
  unsigned int b16p = __shfl(sorted, 15, 64);

  // conservative cut: keep j iff z_j >= z(b16') - 1.001  (score <= z + 1)
  float u16 = __uint_as_float(0x3f800000u | (b16p >> 9)) - 1.0f;
  float z16 = -__logf(-__logf(u16));
  float uc  = __expf(-__expf(-(z16 - 1.001f)));
  unsigned int cp = ((__float_as_uint(1.0f + uc) & 0x7FFFFFu) << 9) & ~1023u;

  // Phase 3: compaction of all survivors (>=16 guaranteed since cut < b16')
  int cnt = 0;
  #pragma unroll
  for (int m = 0; m < 16; ++m) cnt += (v[m] >= cp) ? 1 : 0;
  int s = cnt;
  #pragma unroll
  for (int off = 1; off < 64; off <<= 1){
    int o = __shfl_up(s, off, 64);
    s += (lane >= off) ? o : 0;
  }
  int nc = __shfl(s, 63, 64);
  nc = (nc > 128) ? 128 : nc;
  int slot = s - cnt;
  #pragma unroll
  for (int m = 0; m < 16; ++m){
    if (v[m] >= cp && slot < 128){
      cl[wave][slot] = 1023u - (v[m] & 1023u);
      ++slot;
    }
  }

  // Phase 4: scoring (f32 dist + f32 tail, guarded) + top-16
  const double Td = (double)temp[0];
  const float  Tf = temp[0];
  unsigned long long key;

  if (nc <= 64){
    const bool act1 = (lane < nc);
    const unsigned int jc1 = act1 ? cl[wave][lane] : 0u;
    const float ac1 = dist2_f32(og, &hidf[wave][0], jc1);
    const unsigned int bt1 = tf_bits_part(base | jc1);
    key = tail32(ac1, bt1, jc1, Tf, act1);
    key = bitonic64_desc(key, lane);
    // guard: adjacent top-16 gap below threshold -> exact f64 redo
    double s0 = key_score(key);
    unsigned long long kn = __shfl_down(key, 1, 64);
    double s1 = key_score(kn);
    bool tight = (lane < 16) && (key != 0ull) && ((s0 - s1) < 4e-5);
    if (__any(tight)){
      key = tail64(ac1, bt1, jc1, Td, act1);
      key = bitonic64_desc(key, lane);
    }
  } else {
    // rare two-chunk exact path (v16 verbatim semantics)
    const bool act1 = (lane < nc);
    const unsigned int jc1 = act1 ? cl[wave][lane] : 0u;
    const float ac1 = dist2_f32(og, &hidf[wave][0], jc1);
    const unsigned int bt1 = tf_bits_part(base | jc1);
    key = tail64(ac1, bt1, jc1, Td, act1);
    key = bitonic64_desc(key, lane);

    const int idx2 = 64 + lane;
    const bool act2 = (idx2 < nc);
    const unsigned int jc2 = act2 ? cl[wave][idx2] : 0u;
    const float ac2 = dist2_f32(og, &hidf[wave][0], jc2);
    const unsigned int bt2 = tf_bits_part(base | jc2);
    unsigned long long k2 = tail64(ac2, bt2, jc2, Td, act2);
    k2 = bitonic64_desc(k2, lane);
    unsigned long long kr = __shfl(k2, 63 - lane, 64);
    key = (kr > key) ? kr : key;          // elementwise top-64 (bitonic)
    #pragma unroll
    for (int j2 = 32; j2; j2 >>= 1){      // descending clean
      unsigned long long o = __shfl_xor(key, j2, 64);
      bool left = (lane & j2) == 0;
      bool take = left ? (o > key) : (o < key);
      key = take ? o : key;
    }
  }

  const int grow = (gb << 10) + r;
  if (lane < 16){
    rows_out[((size_t)grow << 4) + lane] = (float)grow;
    cols_out[((size_t)grow << 4) + lane] =
        (float)((gb << 10) + (1023 - (int)(key & 1023ull)));
  }
}

extern "C" void kernel_launch(void* const* d_in, const int* in_sizes, int n_in,
                              void* d_out, int out_size, void* d_ws, size_t ws_size,
                              hipStream_t stream){
  const float* x = (const float*)d_in[0];
  const float* W = (const float*)d_in[1];
  const float* b = (const float*)d_in[2];
  const float* T = (const float*)d_in[3];
  float* out      = (float*)d_out;
  float* rows_out = out + OUT_ELEMS;
  float* cols_out = rows_out + EDGE_ELEMS;

  encoder_v21<<<512, 512, 0, stream>>>(x, W, b, out);
  edges_v21<<<8192, 256, 0, stream>>>(out, T, rows_out, cols_out);
}

// Round 12
// 177.080 us; speedup vs baseline: 1.1426x; 1.0166x over previous
//
#include <hip/hip_runtime.h>
#include <math.h>

// B=32 graphs, N=1024 nodes, D=128 in-dim, C=64 out-dim, K=16.
#define OUT_ELEMS 2097152   // 32768*64
#define EDGE_ELEMS 524288   // 32*1024*16

__device__ __forceinline__ unsigned int rotl32(unsigned int x, int r){
  return (x << r) | (x >> (32 - r));
}

// JAX partitionable threefry, key (0,1): counter = (0, e); out = o0 ^ o1.
__device__ __forceinline__ unsigned int tf_bits_part(unsigned int e){
  unsigned int x0 = 0u, x1 = e;
  const unsigned int ks1 = 1u;
  const unsigned int ks2 = 0x1BD11BDBu;
  x1 += ks1;
#define TFR(r) { x0 += x1; x1 = rotl32(x1, r); x1 ^= x0; }
  TFR(13) TFR(15) TFR(26) TFR(6)
  x0 += ks1; x1 += ks2 + 1u;
  TFR(17) TFR(29) TFR(16) TFR(24)
  x0 += ks2; x1 += 0u + 2u;
  TFR(13) TFR(15) TFR(26) TFR(6)
  x0 += 0u;  x1 += ks1 + 3u;
  TFR(17) TFR(29) TFR(16) TFR(24)
  x0 += ks1; x1 += ks2 + 4u;
  TFR(13) TFR(15) TFR(26) TFR(6)
  x0 += ks2; x1 += 0u + 5u;
#undef TFR
  return x0 ^ x1;
}

// hardware f64 reciprocal + 2 Newton steps: rel err ~1e-16.
__device__ __forceinline__ double rcp64(double x){
  double r;
  asm("v_rcp_f64 %0, %1" : "=v"(r) : "v"(x));
  double e = fma(-x, r, 1.0); r = fma(r, e, r);
  e = fma(-x, r, 1.0); r = fma(r, e, r);
  return r;
}

// fast e^x for x in [-740, ~1]; rel err ~2e-11 (deg-9).
__device__ __forceinline__ double fast_exp(double x){
  double fn = __builtin_rint(x * 1.4426950408889634);
  int n = (int)fn;
  double r = fma(fn, -0.6931471803691238, x);
  r = fma(fn, -1.9082149292705877e-10, r);
  double p = 2.7557319223985893e-06;
  p = fma(r, p, 2.4801587301587302e-05);
  p = fma(r, p, 1.9841269841269841e-04);
  p = fma(r, p, 1.3888888888888889e-03);
  p = fma(r, p, 8.3333333333333333e-03);
  p = fma(r, p, 4.1666666666666664e-02);
  p = fma(r, p, 1.6666666666666666e-01);
  p = fma(r, p, 0.5);
  p = fma(r, p, 1.0);
  p = fma(r, p, 1.0);
  double scale = __longlong_as_double(((long long)(n + 1023)) << 52);
  return p * scale;
}

// fast ln(x), normal positive x; atanh form; abs err ~2e-11.
__device__ __forceinline__ double fast_log(double x){
  long long bx = __double_as_longlong(x);
  long long e = (bx >> 52) - 1023;
  double m = __longlong_as_double((bx & 0xFFFFFFFFFFFFFll) |
                                  0x3FF0000000000000ll);
  int big = m > 1.4142135623730951;
  m = big ? 0.5 * m : m;
  e += big;
  double s = (m - 1.0) * rcp64(m + 1.0);
  double s2 = s * s;
  double p = fma(s2, 2.0/11.0, 2.0/9.0);
  p = fma(s2, p, 2.0/7.0);
  p = fma(s2, p, 2.0/5.0);
  p = fma(s2, p, 2.0/3.0);
  double lm = fma(s * s2, p, 2.0 * s);
  return fma((double)e, 0.6931471805599453, lm);
}

// f32 squared distance; arithmetic identical to v16's score head.
__device__ __forceinline__ float dist2_f32(
    const float* __restrict__ og, const float* __restrict__ hrowf,
    unsigned int jc){
  const float4* cp4 = (const float4*)(og + ((size_t)jc << 6));
  const float4* hp4 = (const float4*)hrowf;
  float a0 = 0.0f, a1 = 0.0f, a2 = 0.0f, a3 = 0.0f;
  #pragma unroll 4
  for (int ch = 0; ch < 16; ++ch){
    float4 cf = cp4[ch];
    float4 hf = hp4[ch];
    float d0 = hf.x - cf.x;
    float d1 = hf.y - cf.y;
    float d2 = hf.z - cf.z;
    float d3 = hf.w - cf.w;
    a0 = fmaf(d0, d0, a0);
    a1 = fmaf(d1, d1, a1);
    a2 = fmaf(d2, d2, a2);
    a3 = fmaf(d3, d3, a3);
  }
  return (a0 + a1) + (a2 + a3);
}

// order-preserving u64 pack, low 10 bits = inverted index (v16 identical).
__device__ __forceinline__ unsigned long long pack_key(double sc,
                                                       unsigned int jc){
  unsigned long long kb = (unsigned long long)__double_as_longlong(sc);
  kb ^= (unsigned long long)(((long long)kb) >> 63) | 0x8000000000000000ull;
  return (kb & ~1023ull) | (unsigned long long)(1023u - jc);
}

// exact f64 tail — keys bit-identical to v16's score_cand32.
__device__ __forceinline__ unsigned long long tail64(
    float accf, unsigned int bits, unsigned int jc, double Td, bool act){
  if (!act) return 0ull;
  double sgm = fast_exp(-Td * (double)accf);
  float f = __uint_as_float(0x3f800000u | (bits >> 9)) - 1.0f;
  double u = (f > 0.0f) ? (double)f : 1.1754943508222875e-38;
  double w = -fast_log(u);
  double z = -fast_log(w);
  double sc = sgm + z;
  return pack_key(sc, jc);
}

// fast f32 tail; |score - tail64 score| <= ~5e-7 (HW exp/log 1-2 ulp).
__device__ __forceinline__ unsigned long long tail32(
    float accf, unsigned int bits, unsigned int jc, float Tf, bool act){
  if (!act) return 0ull;
  float sg = __expf(-Tf * accf);
  float f = __uint_as_float(0x3f800000u | (bits >> 9)) - 1.0f;
  float uf = (f > 0.0f) ? f : 1.17549435e-38f;   // FLT_MIN (normal)
  float wv = -__logf(uf);
  float zf = -__logf(wv);
  double sc = (double)sg + (double)zf;
  return pack_key(sc, jc);
}

// inverse of pack_key's order map (low 10 index bits zeroed: ~2e-13 rel).
__device__ __forceinline__ double key_score(unsigned long long k){
  unsigned long long orig = (k >> 63) ? (k ^ 0x8000000000000000ull) : ~k;
  return __longlong_as_double((long long)(orig & ~1023ull));
}

// Full descending bitonic sort of u64 keys across 64 lanes.
__device__ __forceinline__ unsigned long long bitonic64_desc(
    unsigned long long key, int lane){
  #pragma unroll
  for (int k = 2; k <= 64; k <<= 1){
    #pragma unroll
    for (int j = k >> 1; j; j >>= 1){
      unsigned long long o = __shfl_xor(key, j, 64);
      bool keep_hi = ((lane & k) == 0) == ((lane & j) == 0);
      key = (keep_hi == (o > key)) ? o : key;
    }
  }
  return key;
}

// Full descending bitonic sort of u32 keys across 64 lanes.
__device__ __forceinline__ unsigned int bitonic32_desc(
    unsigned int key, int lane){
  #pragma unroll
  for (int k = 2; k <= 64; k <<= 1){
    #pragma unroll
    for (int j = k >> 1; j; j >>= 1){
      unsigned int o = __shfl_xor(key, j, 64);
      bool keep_hi = ((lane & k) == 0) == ((lane & j) == 0);
      key = (keep_hi == (o > key)) ? o : key;
    }
  }
  return key;
}

// ---------------- prekernel: W,b -> f64 in workspace ----------------
__global__ __launch_bounds__(256) void cvt_wb_v22(
    const float* __restrict__ W, const float* __restrict__ b,
    double* __restrict__ w64, double* __restrict__ b64){
  const int i = blockIdx.x * 256 + threadIdx.x;
  if (i < 8192)      w64[i] = (double)W[i];
  else if (i < 8256) b64[i - 8192] = (double)b[i - 8192];
}

// ---------------- encoder ----------------
// PROVEN-BEST v15/v18 encoder, reverted verbatim. Measured conclusion across
// v10-v21 (8 structures): gfx950 vector FP64 issues at ~1/16 the f32 rate;
// the 4.19M wave-FMA chain has a ~55us issue floor and this feed (s_load W +
// f32-LDS x) is the closest measured (~60us). MFMA-f64 is 8x faster but
// breaks bit-identity (v14 measured fail). Encoder is CLOSED.
__global__ __launch_bounds__(512) void encoder_v22(
    const float* __restrict__ x, const double* __restrict__ w64,
    const double* __restrict__ b64, float* __restrict__ out){
  __shared__ float xs[64 * 129];        // 33 KB, +1-dword pad per row
  const int tid = threadIdx.x;

  { // stage 64x128 x tile, coalesced float4 loads, padded scatter
    const float4* xg4 = (const float4*)(x + ((size_t)blockIdx.x << 13));
    #pragma unroll
    for (int s = 0; s < 4; ++s){
      const int idx = tid + (s << 9);   // 0..2047 float4s
      float4 v = xg4[idx];
      const int r = idx >> 5, k4 = (idx & 31) << 2;
      float* p = &xs[r * 129 + k4];
      p[0] = v.x; p[1] = v.y; p[2] = v.z; p[3] = v.w;
    }
  }
  __syncthreads();

  const int lane = tid & 63;                                  // row
  const int wu = __builtin_amdgcn_readfirstlane(tid >> 6);    // wave (SGPR)
  const int c0 = wu << 3;                                     // 8 cols/wave
  const size_t row = ((size_t)blockIdx.x << 6) + (size_t)lane;

  double acc[8];
  const double* __restrict__ bp = b64 + c0;   // uniform -> s_load
  #pragma unroll
  for (int j = 0; j < 8; ++j) acc[j] = bp[j];

  const float* __restrict__ xrow = &xs[lane * 129];
  #pragma unroll 4
  for (int k = 0; k < 128; ++k){
    const double xk = (double)xrow[k];                 // ds_read + 1 cvt
    const double* __restrict__ wp = w64 + (k << 6) + c0;  // uniform -> s_load
    #pragma unroll
    for (int j = 0; j < 8; ++j)
      acc[j] = fma(xk, wp[j], acc[j]);
  }

  float* __restrict__ orow = out + (row << 6) + c0;
  #pragma unroll
  for (int j2 = 0; j2 < 4; ++j2){
    float2 st; st.x = (float)acc[(j2 << 1)]; st.y = (float)acc[(j2 << 1) + 1];
    *(float2*)&orow[j2 << 1] = st;
  }
}

// ---------------- edges ----------------
// PROVEN v18 (105.5 us, VGPR 32, no spill, absmax 480.0). Issue-saturated
// (VALUBusy ~90%); threefry phase 1 is a ~31us algorithmic floor. CLOSED.
__global__ __launch_bounds__(256, 8) void edges_v22(
    const float* __restrict__ out32, const float* __restrict__ temp,
    float* __restrict__ rows_out, float* __restrict__ cols_out){
  __shared__ float hidf[4][64];         // 1 KB
  __shared__ unsigned int cl[4][128];   // 2 KB
  const int tid = threadIdx.x, wave = tid >> 6, lane = tid & 63;
  const int gb = blockIdx.x >> 8;
  const int i0 = (blockIdx.x & 255) << 2;
  const int r  = i0 + wave;
  const float* __restrict__ og = out32 + ((size_t)gb << 16);

  hidf[wave][lane] = og[((size_t)r << 6) + lane];

  const unsigned int base = ((unsigned int)gb << 20) | ((unsigned int)r << 10);

  // Phase 1: bits for j = m*64 + lane, with running per-lane max
  unsigned int v[16];
  unsigned int pmax = 0u;
  #pragma unroll
  for (int m = 0; m < 16; ++m){
    const unsigned int j = (unsigned int)(m << 6) + (unsigned int)lane;
    unsigned int bits = tf_bits_part(base | j);
    v[m] = (bits & ~1023u) | (1023u - j);   // low 10 bits don't feed u
    pmax = (v[m] > pmax) ? v[m] : pmax;
  }

  // Phase 2: 16th-largest lane-max (conservative surrogate for b16)
  unsigned int sorted = bitonic32_desc(pmax, lane);
  unsigned int b16p = __shfl(sorted, 15, 64);

  // conservative cut: keep j iff z_j >= z(b16') - 1.001  (score <= z + 1)
  float u16 = __uint_as_float(0x3f800000u | (b16p >> 9)) - 1.0f;
  float z16 = -__logf(-__logf(u16));
  float uc  = __expf(-__expf(-(z16 - 1.001f)));
  unsigned int cp = ((__float_as_uint(1.0f + uc) & 0x7FFFFFu) << 9) & ~1023u;

  // Phase 3: compaction of all survivors (>=16 guaranteed since cut < b16')
  int cnt = 0;
  #pragma unroll
  for (int m = 0; m < 16; ++m) cnt += (v[m] >= cp) ? 1 : 0;
  int s = cnt;
  #pragma unroll
  for (int off = 1; off < 64; off <<= 1){
    int o = __shfl_up(s, off, 64);
    s += (lane >= off) ? o : 0;
  }
  int nc = __shfl(s, 63, 64);
  nc = (nc > 128) ? 128 : nc;
  int slot = s - cnt;
  #pragma unroll
  for (int m = 0; m < 16; ++m){
    if (v[m] >= cp && slot < 128){
      cl[wave][slot] = 1023u - (v[m] & 1023u);
      ++slot;
    }
  }

  // Phase 4: scoring (f32 dist + f32 tail, guarded) + top-16
  const double Td = (double)temp[0];
  const float  Tf = temp[0];
  unsigned long long key;

  if (nc <= 64){
    const bool act1 = (lane < nc);
    const unsigned int jc1 = act1 ? cl[wave][lane] : 0u;
    const float ac1 = dist2_f32(og, &hidf[wave][0], jc1);
    const unsigned int bt1 = tf_bits_part(base | jc1);
    key = tail32(ac1, bt1, jc1, Tf, act1);
    key = bitonic64_desc(key, lane);
    // guard: adjacent top-16 gap below threshold -> exact f64 redo
    double s0 = key_score(key);
    unsigned long long kn = __shfl_down(key, 1, 64);
    double s1 = key_score(kn);
    bool tight = (lane < 16) && (key != 0ull) && ((s0 - s1) < 4e-5);
    if (__any(tight)){
      key = tail64(ac1, bt1, jc1, Td, act1);
      key = bitonic64_desc(key, lane);
    }
  } else {
    // rare two-chunk exact path (v16 verbatim semantics)
    const bool act1 = (lane < nc);
    const unsigned int jc1 = act1 ? cl[wave][lane] : 0u;
    const float ac1 = dist2_f32(og, &hidf[wave][0], jc1);
    const unsigned int bt1 = tf_bits_part(base | jc1);
    key = tail64(ac1, bt1, jc1, Td, act1);
    key = bitonic64_desc(key, lane);

    const int idx2 = 64 + lane;
    const bool act2 = (idx2 < nc);
    const unsigned int jc2 = act2 ? cl[wave][idx2] : 0u;
    const float ac2 = dist2_f32(og, &hidf[wave][0], jc2);
    const unsigned int bt2 = tf_bits_part(base | jc2);
    unsigned long long k2 = tail64(ac2, bt2, jc2, Td, act2);
    k2 = bitonic64_desc(k2, lane);
    unsigned long long kr = __shfl(k2, 63 - lane, 64);
    key = (kr > key) ? kr : key;          // elementwise top-64 (bitonic)
    #pragma unroll
    for (int j2 = 32; j2; j2 >>= 1){      // descending clean
      unsigned long long o = __shfl_xor(key, j2, 64);
      bool left = (lane & j2) == 0;
      bool take = left ? (o > key) : (o < key);
      key = take ? o : key;
    }
  }

  const int grow = (gb << 10) + r;
  if (lane < 16){
    rows_out[((size_t)grow << 4) + lane] = (float)grow;
    cols_out[((size_t)grow << 4) + lane] =
        (float)((gb << 10) + (1023 - (int)(key & 1023ull)));
  }
}

extern "C" void kernel_launch(void* const* d_in, const int* in_sizes, int n_in,
                              void* d_out, int out_size, void* d_ws, size_t ws_size,
                              hipStream_t stream){
  const float* x = (const float*)d_in[0];
  const float* W = (const float*)d_in[1];
  const float* b = (const float*)d_in[2];
  const float* T = (const float*)d_in[3];
  float* out      = (float*)d_out;
  float* rows_out = out + OUT_ELEMS;
  float* cols_out = rows_out + EDGE_ELEMS;

  double* w64 = (double*)d_ws;           // 8192 f64 = 64 KB
  double* b64 = w64 + 8192;              // 64 f64

  cvt_wb_v22<<<33, 256, 0, stream>>>(W, b, w64, b64);
  encoder_v22<<<512, 512, 0, stream>>>(x, w64, b64, out);
  edges_v22<<<8192, 256, 0, stream>>>(out, T, rows_out, cols_out);
}